// Round 1
// baseline (561.629 us; speedup 1.0000x reference)
//
#include <hip/hip_runtime.h>
#include <hip/hip_fp16.h>
#include <math.h>

#define TT 1600
#define BB 48
#define VV 1000
#define LL 128
#define TILE 100                      // timesteps per LDS tile
#define NTILES 16                     // 16 * 100 = 1600, all tiles full
#define TILEU (TILE * 64)             // uints per tile buffer (64 uints = 128 halves/row)
#define LN1024 6.93147180559945309f   // emissions pre-scaled by 2^10 -> fp16 normal range

// DPP helper: pure-VALU cross-lane, no LDS counter traffic.
#define DPPF(x, ctrl) __int_as_float(__builtin_amdgcn_update_dpp( \
    0, __float_as_int(x), (ctrl), 0xf, 0xf, true))

typedef const __attribute__((address_space(1))) unsigned int* gldlds_src_t;
typedef __attribute__((address_space(3))) unsigned int*       gldlds_dst_t;

// ---------------------------------------------------------------------------
// K1: coalesced async stage (global_load_lds) -> LDS -> gather+exp -> fp16.
// One block = 8 consecutive (t,b) rows (same t, b0..b0+7; 8 divides 48).
// Outputs:
//   emL half[T][B][128]: emL[t][b][2j..2j+1] = 1024*p(tg[b][2j..2j+1]) at t
//     -> each (t,b) row is 256 B (2 aligned lines); block writes 2 KB contiguous.
//   emB float[B][T]:     emB[b][t] = 1024*p_blank
// ---------------------------------------------------------------------------
__global__ __launch_bounds__(256) void ctc_gather_kernel(
    const float* __restrict__ lp,
    const int* __restrict__ targets,
    __half* __restrict__ emL,
    float* __restrict__ emB)
{
  __shared__ float rb[8000];                   // 8 rows x 1000 floats
  const int tid  = threadIdx.x;
  const int wv   = tid >> 6;
  const int lane = tid & 63;
  const size_t row0 = (size_t)blockIdx.x * 8;

  const float4* src = (const float4*)(lp + row0 * VV);   // 2000 float4, contiguous
#pragma unroll
  for (int i = 0; i < 8; i++) {
    int idx = tid + (i << 8);                  // f4 index; lane-contiguous per wave
    if (idx < 2000)
      __builtin_amdgcn_global_load_lds(
          (gldlds_src_t)(src + idx),
          (gldlds_dst_t)(rb + ((size_t)((i << 8) + (wv << 6)) << 2)),
          16, 0, 0);
  }
  __syncthreads();                             // drains vmcnt

  const int t  = (int)(row0 / BB);
  const int b0 = (int)(row0 % BB);
#pragma unroll
  for (int r = 0; r < 2; r++) {
    const int bl = 2 * wv + r;                 // local row 0..7
    const int b  = b0 + bl;
    const int2 g = ((const int2*)(targets + b * LL))[lane];  // tg[2l], tg[2l+1]
    const float* row = rb + bl * 1000;
    float e0 = __expf(row[g.x] + LN1024);
    float e1 = __expf(row[g.y] + LN1024);
    ((__half2*)emL)[(size_t)(t * BB + b) * 64 + lane] = __floats2half2_rn(e0, e1);
    if (lane == 0) emB[b * TT + t] = __expf(row[0] + LN1024);
  }
}

// ---------------------------------------------------------------------------
// K2: linear-domain scaled CTC forward. One block (4 waves) per batch element.
// Waves 1-3: async-stage 100-step fp16 label tiles (global_load_lds, dbuf LDS)
//            + the whole blank plane once in the prologue.
// Wave 0: DP recurrence, states s = 4*lane + r (+ s=256 as a4 on lane 63).
// Cross-lane via DPP. Rescale deferred one 4-step group (powers of 2 commute
// exactly through the linear recurrence; also absorbs the 1024^t emission
// pre-scale, corrected in closed form at the end).
// ---------------------------------------------------------------------------
__global__ __launch_bounds__(256) void ctc_dp_kernel(
    const __half* __restrict__ emL,
    const float* __restrict__ emB,
    const int* __restrict__ targets,
    const int* __restrict__ input_lengths,
    float* __restrict__ out)
{
  __shared__ unsigned int sbuf[2][TILEU];      // 2 x 25600 B label tiles
  __shared__ float pbbuf[TT];                  // 6400 B blank plane (whole T)
  const int b    = blockIdx.x;
  const int lane = threadIdx.x & 63;
  const int wv   = threadIdx.x >> 6;
  const int NS   = input_lengths[b] - 1;       // steps t = 1..NS

  // ----- consumer lane-local constants -----
  float skip1 = 0.f, skip3 = 0.f, m63 = 0.f, sel1648 = 0.f, sel32 = 0.f;
  if (wv == 0) {
    const int* __restrict__ tg = targets + b * LL;
    const int c0  = tg[2 * lane];
    const int c1  = tg[2 * lane + 1];
    const int cm1 = (lane > 0) ? tg[2 * lane - 1] : c0;
    skip1   = (lane > 0 && c0 != cm1) ? 1.0f : 0.0f;
    skip3   = (c1 != c0) ? 1.0f : 0.0f;
    m63     = (lane == 63) ? 1.0f : 0.0f;
    sel1648 = (lane == 16 || lane == 48) ? 1.0f : 0.0f;
    sel32   = (lane == 32) ? 1.0f : 0.0f;
  }

  float a0 = 0.f, a1 = 0.f, a2 = 0.f, a3 = 0.f, a4 = 0.f;
  int esum = 0;
  float sc_p = 1.0f;                           // pending (deferred) scale
  int   se_p = 0;
  float  pb_r[4];
  float2 ev_r[4];

  // 3 producer waves split the 25 64-f4 groups round-robin. Rows are 256 B,
  // line-aligned; pow-2 index split (idx>>4 = row, idx&15 = 16B chunk).
#define STAGE(KN) do {                                                 \
    const char* srcb_ = (const char*)emL + ((size_t)(KN) * TILE * BB + b) * 256; \
    unsigned int* dst_ = sbuf[(KN) & 1];                               \
    for (int j = wv - 1; j < 25; j += 3) {                             \
      int idx_ = (j << 6) + lane;                                      \
      __builtin_amdgcn_global_load_lds(                                \
          (gldlds_src_t)(srcb_ + (size_t)(idx_ >> 4) * (BB * 256)      \
                               + ((idx_ & 15) << 4)),                  \
          (gldlds_dst_t)(dst_ + (idx_ << 2)), 16, 0, 0);               \
    }                                                                  \
  } while (0)

  // alpha_old[4l-1]: DPP row_shr:1 (row-edge lanes -> 0), patch lanes 16/48
  // from row_bcast15 and lane 32 from row_bcast31.
#define STEP(PB, EV) do {                                            \
    float am1 = DPPF(a3, 0x111);                                     \
    float h15 = DPPF(a3, 0x142);                                     \
    float h31 = DPPF(a3, 0x143);                                     \
    am1 = fmaf(sel1648, h15, am1);                                   \
    am1 = fmaf(sel32,   h31, am1);                                   \
    float s0 = a0 + am1;                                             \
    float s1 = fmaf(skip1, am1, a0 + a1);                            \
    float s2 = a1 + a2;                                              \
    float s3 = fmaf(skip3, a1, a2 + a3);                             \
    float s4 = fmaf(a3, m63, a4);                                    \
    a0 = s0 * (PB); a1 = s1 * (EV).x; a2 = s2 * (PB);                \
    a3 = s3 * (EV).y; a4 = s4 * (PB);                                \
  } while (0)

  // Apply previous group's scale, then start this group's max-reduce; the
  // result is consumed only one group later (latency hidden).
#define RESCALE_DEFERRED() do {                                      \
    a0 *= sc_p; a1 *= sc_p; a2 *= sc_p; a3 *= sc_p; a4 *= sc_p;      \
    esum -= se_p;                                                    \
    float mx = fmaxf(fmaxf(fmaxf(a0, a1), fmaxf(a2, a3)), a4);       \
    mx = fmaxf(mx, DPPF(mx, 0x111));                                 \
    mx = fmaxf(mx, DPPF(mx, 0x112));                                 \
    mx = fmaxf(mx, DPPF(mx, 0x114));                                 \
    mx = fmaxf(mx, DPPF(mx, 0x118));                                 \
    mx = fmaxf(mx, DPPF(mx, 0x142));                                 \
    mx = fmaxf(mx, DPPF(mx, 0x143));     /* lane63 = wave max */     \
    int eb = (__builtin_amdgcn_readlane(__float_as_int(mx), 63) >> 23) & 0xFF; \
    int se = 157 - eb;                   /* aim max at ~2^30 */      \
    se = se < -126 ? -126 : (se > 127 ? 127 : se);                   \
    sc_p = __uint_as_float((unsigned)(se + 127) << 23);              \
    se_p = se;                                                       \
  } while (0)

  if (wv) {
    // blank plane: 1600 floats = 400 x 16 B, staged once
    for (int j = wv - 1; j < 7; j += 3) {
      int idx = (j << 6) + lane;
      if (idx < 400)
        __builtin_amdgcn_global_load_lds(
            (gldlds_src_t)(emB + (size_t)b * TT + ((size_t)idx << 2)),
            (gldlds_dst_t)(pbbuf + (idx << 2)), 16, 0, 0);
    }
    STAGE(0);
  }
  __syncthreads();

  for (int k = 0; k < NTILES; k++) {
    if (wv) {
      if (k + 1 < NTILES) STAGE(k + 1);
    } else {
      const unsigned int* tb = sbuf[k & 1];
      if (k == 0 && lane == 0) {               // t=0 init
        a0 = pbbuf[0];
        unsigned int u0 = tb[0];
        a1 = __half22float2(*reinterpret_cast<const __half2*>(&u0)).x;
      }
      int tbeg = (k == 0) ? 1 : k * TILE;
      int tend = k * TILE + TILE - 1;
      if (tend > NS) tend = NS;
      int n = tend - tbeg + 1;
      if (n > 0) {
        const unsigned int* lb0 = tb + (tbeg - k * TILE) * 64 + lane;
#define LOADSLOT(D, TF) do {                                         \
    pb_r[D] = pbbuf[tbeg + (TF)];            /* uniform -> bcast */  \
    unsigned int u_ = lb0[(TF) * 64];        /* 2-way alias: free */ \
    ev_r[D] = __half22float2(*reinterpret_cast<const __half2*>(&u_)); \
  } while (0)
#pragma unroll
        for (int d = 0; d < 4; d++) { if (d < n) LOADSLOT(d, d); }
        int i = 0;
        while (i + 4 <= n) {
#pragma unroll
          for (int d = 0; d < 4; d++) {
            STEP(pb_r[d], ev_r[d]);
            int tf = i + 4 + d;
            if (tf < n) LOADSLOT(d, tf);
          }
          RESCALE_DEFERRED();
          i += 4;
        }
#pragma unroll
        for (int d = 0; d < 3; d++) {
          if (i + d < n) STEP(pb_r[d], ev_r[d]);
        }
#undef LOADSLOT
      }
    }
    __syncthreads();
  }

  if (wv == 0 && lane == 63) {
    a3 *= sc_p; a4 *= sc_p; esum -= se_p;      // flush pending scale
    // alpha[255] = a3, alpha[256] = a4; stored = true * 1024^(NS+1) * 2^-esum
    float tot = __logf(a3 + a4)
              + ((float)esum - 10.0f * (float)(NS + 1)) * 0.69314718055994530942f;
    atomicAdd(out, -tot);
  }
#undef STEP
#undef RESCALE_DEFERRED
#undef STAGE
}

// ---------------------------------------------------------------------------
extern "C" void kernel_launch(void* const* d_in, const int* in_sizes, int n_in,
                              void* d_out, int out_size, void* d_ws, size_t ws_size,
                              hipStream_t stream) {
  const float* lp            = (const float*)d_in[0];
  const int*   targets       = (const int*)d_in[1];
  const int*   input_lengths = (const int*)d_in[2];

  float*  emB = (float*)d_ws;                         // 307,200 B blank plane
  __half* emL = (__half*)((char*)d_ws + 307200);      // 19.66 MB label plane
  float*  out = (float*)d_out;

  hipMemsetAsync(out, 0, sizeof(float), stream);

  ctc_gather_kernel<<<(TT * BB) / 8, 256, 0, stream>>>(lp, targets, emL, emB);
  ctc_dp_kernel<<<BB, 256, 0, stream>>>(emL, emB, targets, input_lengths, out);
}

// Round 2
// 545.161 us; speedup vs baseline: 1.0302x; 1.0302x over previous
//
#include <hip/hip_runtime.h>
#include <hip/hip_fp16.h>
#include <math.h>

#define TT 1600
#define BB 48
#define VV 1000
#define LL 128
#define TILE 100                      // timesteps per LDS tile
#define NTILES 16                     // 16 * 100 = 1600, all tiles full
#define TILEU (TILE * 64)             // uints per tile buffer (64 uints = 128 halves/row)
#define LN1024 6.93147180559945309f   // emissions pre-scaled by 2^10 -> fp16 normal range

// DPP helper: pure-VALU cross-lane, no LDS counter traffic.
#define DPPF(x, ctrl) __int_as_float(__builtin_amdgcn_update_dpp( \
    0, __float_as_int(x), (ctrl), 0xf, 0xf, true))

typedef const __attribute__((address_space(1))) unsigned int* gldlds_src_t;
typedef __attribute__((address_space(3))) unsigned int*       gldlds_dst_t;

// ---------------------------------------------------------------------------
// K1: coalesced async stage (global_load_lds) -> LDS -> gather+exp -> fp16.
// One block = 4 consecutive (t,b) rows (same t, b0..b0+3; 4 divides 48).
// 16 KB LDS -> 8 blocks/CU (wave-limited), vs 5 with 32 KB: better tail hiding.
// Outputs:
//   emL half[T][B][128]: emL[t][b][2j..2j+1] = 1024*p(tg[b][2j..2j+1]) at t
//   emB float[B][T]:     emB[b][t] = 1024*p_blank
// Block 0 also zeroes *out (replaces the hipMemsetAsync dispatch; K2 runs
// strictly after K1 in stream order).
// ---------------------------------------------------------------------------
__global__ __launch_bounds__(256) void ctc_gather_kernel(
    const float* __restrict__ lp,
    const int* __restrict__ targets,
    __half* __restrict__ emL,
    float* __restrict__ emB,
    float* __restrict__ out)
{
  __shared__ float rb[4000];                   // 4 rows x 1000 floats
  const int tid  = threadIdx.x;
  const int wv   = tid >> 6;
  const int lane = tid & 63;
  const size_t row0 = (size_t)blockIdx.x * 4;

  if (blockIdx.x == 0 && tid == 0) *out = 0.0f;

  const float4* src = (const float4*)(lp + row0 * VV);   // 1000 float4, contiguous
#pragma unroll
  for (int i = 0; i < 4; i++) {
    int idx = tid + (i << 8);                  // f4 index; lane-contiguous per wave
    if (idx < 1000)
      __builtin_amdgcn_global_load_lds(
          (gldlds_src_t)(src + idx),
          (gldlds_dst_t)(rb + ((size_t)((i << 8) + (wv << 6)) << 2)),
          16, 0, 0);
  }
  __syncthreads();                             // drains vmcnt

  const int t  = (int)(row0 / BB);
  const int b0 = (int)(row0 % BB);
  const int b  = b0 + wv;                      // one row per wave
  const int2 g = ((const int2*)(targets + b * LL))[lane];  // tg[2l], tg[2l+1]
  const float* row = rb + wv * 1000;
  float e0 = __expf(row[g.x] + LN1024);
  float e1 = __expf(row[g.y] + LN1024);
  ((__half2*)emL)[(size_t)(t * BB + b) * 64 + lane] = __floats2half2_rn(e0, e1);
  if (lane == 0) emB[b * TT + t] = __expf(row[0] + LN1024);
}

// ---------------------------------------------------------------------------
// K2: linear-domain scaled CTC forward. One block (4 waves) per batch element.
// Waves 1-3: async-stage 100-step fp16 label tiles (global_load_lds, dbuf LDS)
//            + the whole blank plane once in the prologue.
// Wave 0: DP recurrence, states s = 4*lane + r (+ s=256 as a4 on lane 63).
// Cross-lane via DPP. Rescale deferred one 8-step group (powers of 2 commute
// exactly through the linear recurrence; also absorbs the 1024^t emission
// pre-scale, corrected in closed form at the end). Target max ~2^6 leaves
// ~2^88 of headroom for two groups of worst-case growth (<=2^5.5/step here).
// LDS ev prefetch is 8 slots (~128 cyc) deep, covering ds_read latency.
// ---------------------------------------------------------------------------
__global__ __launch_bounds__(256) void ctc_dp_kernel(
    const __half* __restrict__ emL,
    const float* __restrict__ emB,
    const int* __restrict__ targets,
    const int* __restrict__ input_lengths,
    float* __restrict__ out)
{
  __shared__ unsigned int sbuf[2][TILEU];      // 2 x 25600 B label tiles
  __shared__ float pbbuf[TT];                  // 6400 B blank plane (whole T)
  const int b    = blockIdx.x;
  const int lane = threadIdx.x & 63;
  const int wv   = threadIdx.x >> 6;
  const int NS   = input_lengths[b] - 1;       // steps t = 1..NS

  // ----- consumer lane-local constants -----
  float skip1 = 0.f, skip3 = 0.f, m63 = 0.f, sel1648 = 0.f, sel32 = 0.f;
  if (wv == 0) {
    const int* __restrict__ tg = targets + b * LL;
    const int c0  = tg[2 * lane];
    const int c1  = tg[2 * lane + 1];
    const int cm1 = (lane > 0) ? tg[2 * lane - 1] : c0;
    skip1   = (lane > 0 && c0 != cm1) ? 1.0f : 0.0f;
    skip3   = (c1 != c0) ? 1.0f : 0.0f;
    m63     = (lane == 63) ? 1.0f : 0.0f;
    sel1648 = (lane == 16 || lane == 48) ? 1.0f : 0.0f;
    sel32   = (lane == 32) ? 1.0f : 0.0f;
  }

  float a0 = 0.f, a1 = 0.f, a2 = 0.f, a3 = 0.f, a4 = 0.f;
  int esum = 0;
  float sc_p = 1.0f;                           // pending (deferred) scale
  int   se_p = 0;
  float  pb_r[8];
  float2 ev_r[8];

  // 3 producer waves split the 25 64-f4 groups round-robin. Rows are 256 B,
  // line-aligned; pow-2 index split (idx>>4 = row, idx&15 = 16B chunk).
#define STAGE(KN) do {                                                 \
    const char* srcb_ = (const char*)emL + ((size_t)(KN) * TILE * BB + b) * 256; \
    unsigned int* dst_ = sbuf[(KN) & 1];                               \
    for (int j = wv - 1; j < 25; j += 3) {                             \
      int idx_ = (j << 6) + lane;                                      \
      __builtin_amdgcn_global_load_lds(                                \
          (gldlds_src_t)(srcb_ + (size_t)(idx_ >> 4) * (BB * 256)      \
                               + ((idx_ & 15) << 4)),                  \
          (gldlds_dst_t)(dst_ + (idx_ << 2)), 16, 0, 0);               \
    }                                                                  \
  } while (0)

  // alpha_old[4l-1]: DPP row_shr:1 (row-edge lanes -> 0), patch lanes 16/48
  // from row_bcast15 and lane 32 from row_bcast31.
#define STEP(PB, EV) do {                                            \
    float am1 = DPPF(a3, 0x111);                                     \
    float h15 = DPPF(a3, 0x142);                                     \
    float h31 = DPPF(a3, 0x143);                                     \
    am1 = fmaf(sel1648, h15, am1);                                   \
    am1 = fmaf(sel32,   h31, am1);                                   \
    float s0 = a0 + am1;                                             \
    float s1 = fmaf(skip1, am1, a0 + a1);                            \
    float s2 = a1 + a2;                                              \
    float s3 = fmaf(skip3, a1, a2 + a3);                             \
    float s4 = fmaf(a3, m63, a4);                                    \
    a0 = s0 * (PB); a1 = s1 * (EV).x; a2 = s2 * (PB);                \
    a3 = s3 * (EV).y; a4 = s4 * (PB);                                \
  } while (0)

  // Apply previous group's scale, then start this group's max-reduce; the
  // result is consumed only one group later (latency hidden).
#define RESCALE_DEFERRED() do {                                      \
    a0 *= sc_p; a1 *= sc_p; a2 *= sc_p; a3 *= sc_p; a4 *= sc_p;      \
    esum -= se_p;                                                    \
    float mx = fmaxf(fmaxf(fmaxf(a0, a1), fmaxf(a2, a3)), a4);       \
    mx = fmaxf(mx, DPPF(mx, 0x111));                                 \
    mx = fmaxf(mx, DPPF(mx, 0x112));                                 \
    mx = fmaxf(mx, DPPF(mx, 0x114));                                 \
    mx = fmaxf(mx, DPPF(mx, 0x118));                                 \
    mx = fmaxf(mx, DPPF(mx, 0x142));                                 \
    mx = fmaxf(mx, DPPF(mx, 0x143));     /* lane63 = wave max */     \
    int eb = (__builtin_amdgcn_readlane(__float_as_int(mx), 63) >> 23) & 0xFF; \
    int se = 133 - eb;                   /* aim max at ~2^6 */       \
    se = se < -126 ? -126 : (se > 127 ? 127 : se);                   \
    sc_p = __uint_as_float((unsigned)(se + 127) << 23);              \
    se_p = se;                                                       \
  } while (0)

  if (wv) {
    // blank plane: 1600 floats = 400 x 16 B, staged once
    for (int j = wv - 1; j < 7; j += 3) {
      int idx = (j << 6) + lane;
      if (idx < 400)
        __builtin_amdgcn_global_load_lds(
            (gldlds_src_t)(emB + (size_t)b * TT + ((size_t)idx << 2)),
            (gldlds_dst_t)(pbbuf + (idx << 2)), 16, 0, 0);
    }
    STAGE(0);
  }
  __syncthreads();

  for (int k = 0; k < NTILES; k++) {
    if (wv) {
      if (k + 1 < NTILES) STAGE(k + 1);
    } else {
      const unsigned int* tb = sbuf[k & 1];
      if (k == 0 && lane == 0) {               // t=0 init
        a0 = pbbuf[0];
        unsigned int u0 = tb[0];
        a1 = __half22float2(*reinterpret_cast<const __half2*>(&u0)).x;
      }
      int tbeg = (k == 0) ? 1 : k * TILE;
      int tend = k * TILE + TILE - 1;
      if (tend > NS) tend = NS;
      int n = tend - tbeg + 1;
      if (n > 0) {
        const unsigned int* lb0 = tb + (tbeg - k * TILE) * 64 + lane;
#define LOADSLOT(D, TF) do {                                         \
    pb_r[D] = pbbuf[tbeg + (TF)];            /* uniform -> bcast */  \
    unsigned int u_ = lb0[(TF) * 64];        /* 2-way alias: free */ \
    ev_r[D] = __half22float2(*reinterpret_cast<const __half2*>(&u_)); \
  } while (0)
#pragma unroll
        for (int d = 0; d < 8; d++) { if (d < n) LOADSLOT(d, d); }
        int i = 0;
        while (i + 8 <= n) {
#pragma unroll
          for (int d = 0; d < 8; d++) {
            STEP(pb_r[d], ev_r[d]);
            int tf = i + 8 + d;
            if (tf < n) LOADSLOT(d, tf);
          }
          RESCALE_DEFERRED();
          i += 8;
        }
#pragma unroll
        for (int d = 0; d < 7; d++) {
          if (i + d < n) STEP(pb_r[d], ev_r[d]);
        }
#undef LOADSLOT
      }
    }
    __syncthreads();
  }

  if (wv == 0 && lane == 63) {
    a3 *= sc_p; a4 *= sc_p; esum -= se_p;      // flush pending scale
    // alpha[255] = a3, alpha[256] = a4; stored = true * 1024^(NS+1) * 2^-esum
    float tot = __logf(a3 + a4)
              + ((float)esum - 10.0f * (float)(NS + 1)) * 0.69314718055994530942f;
    atomicAdd(out, -tot);
  }
#undef STEP
#undef RESCALE_DEFERRED
#undef STAGE
}

// ---------------------------------------------------------------------------
extern "C" void kernel_launch(void* const* d_in, const int* in_sizes, int n_in,
                              void* d_out, int out_size, void* d_ws, size_t ws_size,
                              hipStream_t stream) {
  const float* lp            = (const float*)d_in[0];
  const int*   targets       = (const int*)d_in[1];
  const int*   input_lengths = (const int*)d_in[2];

  float*  emB = (float*)d_ws;                         // 307,200 B blank plane
  __half* emL = (__half*)((char*)d_ws + 307200);      // 19.66 MB label plane
  float*  out = (float*)d_out;

  ctc_gather_kernel<<<(TT * BB) / 4, 256, 0, stream>>>(lp, targets, emL, emB, out);
  ctc_dp_kernel<<<BB, 256, 0, stream>>>(emL, emB, targets, input_lengths, out);
}